// Round 4
// baseline (538.286 us; speedup 1.0000x reference)
//
#include <hip/hip_runtime.h>
#include <stdint.h>

#define BATCH 8
#define SEQ   4096
#define DIM   1024
#define ROWS  (BATCH * SEQ)   // 32768
#define NT    (SEQ / 128)     // 32 tiles per dim
#define NPAIR (NT * (NT + 1) / 2)  // 528 triangular tile pairs

typedef __attribute__((ext_vector_type(8))) short short8;
typedef __attribute__((ext_vector_type(4))) float f32x4;

__device__ __forceinline__ unsigned short f2bf(float f) {
  union { float f; unsigned u; } v; v.f = f;
  unsigned r = v.u + 0x7FFFu + ((v.u >> 16) & 1u);  // RNE
  return (unsigned short)(r >> 16);
}
__device__ __forceinline__ float bf2f(unsigned short h) {
  union { unsigned u; float f; } v; v.u = ((unsigned)h) << 16;
  return v.f;
}

__device__ __forceinline__ void gload_lds16(const unsigned short* g, unsigned short* l) {
  __builtin_amdgcn_global_load_lds(
      (const __attribute__((address_space(1))) void*)g,
      (__attribute__((address_space(3))) void*)l,
      16, 0, 0);
}

__device__ __forceinline__ f32x4 mfma16(short8 a, short8 b, f32x4 c) {
  return __builtin_amdgcn_mfma_f32_16x16x32_bf16(a, b, c, 0, 0, 0);
}

// Stage a [128 rows][64 k] bf16 tile into linear LDS (16 KiB) via global_load_lds.
// XOR swizzle (chunk ^ (row&7)) applied on the GLOBAL source (rule #21).
__device__ __forceinline__ void stage_tile(const unsigned short* __restrict__ src,
                                           int row0, int k0,
                                           unsigned short* lds, int tid) {
#pragma unroll
  for (int i = 0; i < 4; ++i) {
    int s   = tid + 256 * i;      // 16B chunk slot, 1024 chunks total
    int row = s >> 3;             // 8 chunks (128B) per row
    int h   = s & 7;
    int gc  = h ^ (row & 7);      // inverse-swizzled source chunk
    const unsigned short* gp = src + (size_t)(row0 + row) * DIM + (size_t)(k0 + gc * 8);
    unsigned short* lp = lds + (size_t)((tid & ~63) + 256 * i) * 8;  // wave-uniform base
    gload_lds16(gp, lp);
  }
}

// Read one MFMA A/B fragment (contiguous k-permutation, ds_read_b128),
// applying the same XOR swizzle as the staging side.
__device__ __forceinline__ short8 read_frag(const unsigned short* lds, int rowbase,
                                            int r16, int g, int kk) {
  int row  = rowbase + r16;                 // rowbase multiple of 16 -> row&7 == r16&7
  int slot = (g + 4 * kk) ^ (r16 & 7);
  return *(const short8*)(lds + (size_t)row * 64 + (size_t)slot * 8);
}

// ---------------------------------------------------------------------------
__global__ void init_zero_k(float* __restrict__ out, float* __restrict__ norm2) {
  int i = blockIdx.x * 256 + threadIdx.x;
  if (i < ROWS) { out[i] = 0.f; norm2[i] = 0.f; }
}

__global__ void convert_x_k(const float4* __restrict__ x, ushort4* __restrict__ xb, int n4) {
  int i = blockIdx.x * 256 + threadIdx.x;
  if (i < n4) {
    float4 v = x[i];
    ushort4 o;
    o.x = f2bf(v.x); o.y = f2bf(v.y); o.z = f2bf(v.z); o.w = f2bf(v.w);
    xb[i] = o;
  }
}

// Wt[n][k] = W[k][n], bf16.  64x64 tiles via LDS.
__global__ void transpose_w_k(const float* __restrict__ W, unsigned short* __restrict__ Wt) {
  __shared__ unsigned short t[64][65];
  int bx = blockIdx.x & 15;   // col tile of W
  int by = blockIdx.x >> 4;   // row tile of W
  int c  = threadIdx.x & 63;
  int r0 = threadIdx.x >> 6;  // 0..3
#pragma unroll
  for (int i = 0; i < 16; ++i) {
    int r = r0 + i * 4;
    t[r][c] = f2bf(W[(size_t)(by * 64 + r) * DIM + (bx * 64 + c)]);
  }
  __syncthreads();
#pragma unroll
  for (int i = 0; i < 16; ++i) {
    int r = r0 + i * 4;  // row of Wt within tile = original col
    Wt[(size_t)(bx * 64 + r) * DIM + (by * 64 + c)] = t[c][r];
  }
}

// ---------------------------------------------------------------------------
// GEMM1: proj = Xb @ W  (B panel = rows of Wt). Writes bf16 proj + atomic sumsq.
// XCD-aware remap: each XCD gets a contiguous 32-mt chunk (all nt) -> Wt (2 MiB)
// becomes L2-resident per XCD; norm2 atomics stay XCD-local.
__global__ __launch_bounds__(256) void gemm1_proj(
    const unsigned short* __restrict__ Xb,
    const unsigned short* __restrict__ Wt,
    unsigned short* __restrict__ projb,
    float* __restrict__ norm2) {
  __shared__ __align__(16) unsigned short lA[128 * 64];
  __shared__ __align__(16) unsigned short lB[128 * 64];
  const int tid = threadIdx.x;
  const int lane = tid & 63, wv = tid >> 6;
  const int wr = wv >> 1, wc = wv & 1;
  const int g = lane >> 4, r16 = lane & 15;
  const int flat = blockIdx.x;                       // 2048 blocks
  const int swz  = (flat & 7) * 256 + (flat >> 3);   // XCD k -> swz in [k*256,(k+1)*256)
  const int mt = swz >> 3, nt = swz & 7;
  const int arow0 = mt * 128, brow0 = nt * 128;

  f32x4 acc[4][4];
#pragma unroll
  for (int m = 0; m < 4; ++m)
#pragma unroll
    for (int n = 0; n < 4; ++n) acc[m][n] = (f32x4){0.f, 0.f, 0.f, 0.f};

  for (int kt = 0; kt < DIM / 64; ++kt) {
    stage_tile(Xb, arow0, kt * 64, lA, tid);
    stage_tile(Wt, brow0, kt * 64, lB, tid);
    __syncthreads();
#pragma unroll
    for (int kk = 0; kk < 2; ++kk) {
      short8 af[4], bfr[4];
#pragma unroll
      for (int m = 0; m < 4; ++m) af[m] = read_frag(lA, wr * 64 + m * 16, r16, g, kk);
#pragma unroll
      for (int n = 0; n < 4; ++n) bfr[n] = read_frag(lB, wc * 64 + n * 16, r16, g, kk);
#pragma unroll
      for (int m = 0; m < 4; ++m)
#pragma unroll
        for (int n = 0; n < 4; ++n)
          acc[m][n] = mfma16(af[m], bfr[n], acc[m][n]);
    }
    __syncthreads();
  }

  // Epilogue: bf16 store + per-row sum-of-squares (reduce over lane&15 = cols).
#pragma unroll
  for (int m = 0; m < 4; ++m) {
#pragma unroll
    for (int r = 0; r < 4; ++r) {
      int row = arow0 + wr * 64 + m * 16 + 4 * g + r;
      float ss = 0.f;
#pragma unroll
      for (int n = 0; n < 4; ++n) {
        float v = acc[m][n][r];
        projb[(size_t)row * DIM + (brow0 + wc * 64 + n * 16 + r16)] = f2bf(v);
        ss += v * v;
      }
      ss += __shfl_xor(ss, 1);
      ss += __shfl_xor(ss, 2);
      ss += __shfl_xor(ss, 4);
      ss += __shfl_xor(ss, 8);
      if (r16 == 0) atomicAdd(&norm2[row], ss);
    }
  }
}

// ---------------------------------------------------------------------------
// GEMM2 (symmetric): only tiles st <= tt. Raw-dot MFMA on unnormalized projb;
// epilogue scales by rs_s*rs_t (rs = 1/max(||p||, eps)), applies sigmoid, and
// accumulates BOTH col-sums (-> out[t in C]) and, for off-diagonal tiles,
// row-sums (-> out[s in R], by symmetry sim[s,t]=sim[t,s]).
// XCD-aware remap: 4224 blocks = 8 XCDs x 528 pairs -> XCD k runs batch k
// entirely (st-major order: A-panel L2-hot, batch panel L3-resident, out
// atomics XCD-local).
__global__ __launch_bounds__(256) void gemm2_attn(
    const unsigned short* __restrict__ projb,
    const float* __restrict__ norm2,
    float* __restrict__ out) {
  __shared__ __align__(16) unsigned short lA[128 * 64];
  __shared__ __align__(16) unsigned short lB[128 * 64];
  const int tid = threadIdx.x;
  const int lane = tid & 63, wv = tid >> 6;
  const int wr = wv >> 1, wc = wv & 1;
  const int g = lane >> 4, r16 = lane & 15;

  // flat id in HW dispatch order (x fastest), then bijective XCD remap.
  const int flat = blockIdx.z * NPAIR + blockIdx.x;  // [0, 4224)
  const int b = flat & 7;                            // XCD k <- batch k
  int p = flat >> 3;                                 // [0, 528), st-major

  // Decode triangular pair index p -> (st, tt), st <= tt. Uniform scalar loop.
  int st = 0, rem = p;
  while (rem >= (NT - st)) { rem -= (NT - st); ++st; }
  const int tt = st + rem;

  const unsigned short* Nb = projb + (size_t)b * SEQ * DIM;
  const float* n2b = norm2 + (size_t)b * SEQ;
  const int arow0 = st * 128, brow0 = tt * 128;
  const bool diag = (st == tt);

  f32x4 acc[4][4];
#pragma unroll
  for (int m = 0; m < 4; ++m)
#pragma unroll
    for (int n = 0; n < 4; ++n) acc[m][n] = (f32x4){0.f, 0.f, 0.f, 0.f};

  for (int kt = 0; kt < DIM / 64; ++kt) {
    stage_tile(Nb, arow0, kt * 64, lA, tid);
    if (!diag) stage_tile(Nb, brow0, kt * 64, lB, tid);
    __syncthreads();
    const unsigned short* lBr = diag ? lA : lB;
#pragma unroll
    for (int kk = 0; kk < 2; ++kk) {
      short8 af[4], bfr[4];
#pragma unroll
      for (int m = 0; m < 4; ++m) af[m] = read_frag(lA, wr * 64 + m * 16, r16, g, kk);
#pragma unroll
      for (int n = 0; n < 4; ++n) bfr[n] = read_frag(lBr, wc * 64 + n * 16, r16, g, kk);
#pragma unroll
      for (int m = 0; m < 4; ++m)
#pragma unroll
        for (int n = 0; n < 4; ++n)
          acc[m][n] = mfma16(af[m], bfr[n], acc[m][n]);
    }
    __syncthreads();
  }

  // Inverse norms for my rows (16) and cols (4).  rs = 1/max(sqrt(ss), eps).
  float rs_row[4][4], rs_col[4];
#pragma unroll
  for (int m = 0; m < 4; ++m)
#pragma unroll
    for (int r = 0; r < 4; ++r) {
      int row = arow0 + wr * 64 + m * 16 + 4 * g + r;
      rs_row[m][r] = 1.0f / fmaxf(sqrtf(n2b[row]), 1e-12f);
    }
#pragma unroll
  for (int n = 0; n < 4; ++n) {
    int col = brow0 + wc * 64 + n * 16 + r16;
    rs_col[n] = 1.0f / fmaxf(sqrtf(n2b[col]), 1e-12f);
  }

  const float inv = 1.0f / (float)SEQ;
  float rowacc[4][4];
#pragma unroll
  for (int m = 0; m < 4; ++m)
#pragma unroll
    for (int r = 0; r < 4; ++r) rowacc[m][r] = 0.f;

  // Sigmoid each element once; accumulate col partials (per n) + row partials.
#pragma unroll
  for (int n = 0; n < 4; ++n) {
    float colpart = 0.f;
#pragma unroll
    for (int m = 0; m < 4; ++m)
#pragma unroll
      for (int r = 0; r < 4; ++r) {
        float x = acc[m][n][r] * rs_row[m][r] * rs_col[n];
        float s = 1.0f / (1.0f + __expf(-x));
        colpart += s;
        rowacc[m][r] += s;
      }
    // reduce over rows held by other g-groups of this wave
    colpart += __shfl_xor(colpart, 16);
    colpart += __shfl_xor(colpart, 32);
    if (g == 0)
      atomicAdd(&out[(size_t)b * SEQ + brow0 + wc * 64 + n * 16 + r16], colpart * inv);
  }

  if (!diag) {
    // row sums over this wave's 64 cols -> out[s in R] (symmetry).
#pragma unroll
    for (int m = 0; m < 4; ++m)
#pragma unroll
      for (int r = 0; r < 4; ++r) {
        float rp = rowacc[m][r];
        rp += __shfl_xor(rp, 1);
        rp += __shfl_xor(rp, 2);
        rp += __shfl_xor(rp, 4);
        rp += __shfl_xor(rp, 8);
        if (r16 == 0)
          atomicAdd(&out[(size_t)b * SEQ + arow0 + wr * 64 + m * 16 + 4 * g + r], rp * inv);
      }
  }
}

// ---------------------------------------------------------------------------
extern "C" void kernel_launch(void* const* d_in, const int* in_sizes, int n_in,
                              void* d_out, int out_size, void* d_ws, size_t ws_size,
                              hipStream_t stream) {
  const float* x = (const float*)d_in[0];
  const float* W = (const float*)d_in[1];
  float* out = (float*)d_out;

  char* ws = (char*)d_ws;
  unsigned short* Xb    = (unsigned short*)ws;                                   // 64 MiB
  unsigned short* projb = (unsigned short*)(ws + (size_t)ROWS * DIM * 2);        // 64 MiB
  unsigned short* Wt    = (unsigned short*)(ws + (size_t)ROWS * DIM * 4);        // 2 MiB
  float* norm2          = (float*)(ws + (size_t)ROWS * DIM * 4 + (size_t)DIM * DIM * 2);

  hipLaunchKernelGGL(init_zero_k, dim3(ROWS / 256), dim3(256), 0, stream, out, norm2);
  hipLaunchKernelGGL(convert_x_k, dim3((ROWS * DIM / 4) / 256), dim3(256), 0, stream,
                     (const float4*)x, (ushort4*)Xb, ROWS * DIM / 4);
  hipLaunchKernelGGL(transpose_w_k, dim3(256), dim3(256), 0, stream, W, Wt);
  hipLaunchKernelGGL(gemm1_proj, dim3((ROWS / 128) * (DIM / 128)), dim3(256), 0, stream,
                     Xb, Wt, projb, norm2);
  hipLaunchKernelGGL(gemm2_attn, dim3(NPAIR, 1, BATCH), dim3(256), 0, stream,
                     projb, norm2, out);
}

// Round 7
// 520.518 us; speedup vs baseline: 1.0341x; 1.0341x over previous
//
#include <hip/hip_runtime.h>
#include <stdint.h>

#define BATCH 8
#define SEQ   4096
#define DIM   1024
#define ROWS  (BATCH * SEQ)   // 32768
#define NT    (SEQ / 128)     // 32 tiles per dim
#define NPAIR (NT * (NT + 1) / 2)  // 528 triangular tile pairs
#define TILE  (128 * 64)      // elements per LDS tile buffer

typedef __attribute__((ext_vector_type(8))) short short8;
typedef __attribute__((ext_vector_type(4))) float f32x4;

__device__ __forceinline__ unsigned short f2bf(float f) {
  union { float f; unsigned u; } v; v.f = f;
  unsigned r = v.u + 0x7FFFu + ((v.u >> 16) & 1u);  // RNE
  return (unsigned short)(r >> 16);
}
__device__ __forceinline__ float bf2f(unsigned short h) {
  union { unsigned u; float f; } v; v.u = ((unsigned)h) << 16;
  return v.f;
}

__device__ __forceinline__ void gload_lds16(const unsigned short* g, unsigned short* l) {
  __builtin_amdgcn_global_load_lds(
      (const __attribute__((address_space(1))) void*)g,
      (__attribute__((address_space(3))) void*)l,
      16, 0, 0);
}

__device__ __forceinline__ f32x4 mfma16(short8 a, short8 b, f32x4 c) {
  return __builtin_amdgcn_mfma_f32_16x16x32_bf16(a, b, c, 0, 0, 0);
}

// Stage a [128 rows][64 k] bf16 tile into linear LDS (16 KiB) via global_load_lds.
// XOR swizzle (chunk ^ (row&7)) applied on the GLOBAL source (rule #21).
__device__ __forceinline__ void stage_tile(const unsigned short* __restrict__ src,
                                           int row0, int k0,
                                           unsigned short* lds, int tid) {
#pragma unroll
  for (int i = 0; i < 4; ++i) {
    int s   = tid + 256 * i;      // 16B chunk slot, 1024 chunks total
    int row = s >> 3;             // 8 chunks (128B) per row
    int h   = s & 7;
    int gc  = h ^ (row & 7);      // inverse-swizzled source chunk
    const unsigned short* gp = src + (size_t)(row0 + row) * DIM + (size_t)(k0 + gc * 8);
    unsigned short* lp = lds + (size_t)((tid & ~63) + 256 * i) * 8;  // wave-uniform base
    gload_lds16(gp, lp);
  }
}

// Read one MFMA A/B fragment (contiguous k-permutation, ds_read_b128),
// applying the same XOR swizzle as the staging side.
__device__ __forceinline__ short8 read_frag(const unsigned short* lds, int rowbase,
                                            int r16, int g, int kk) {
  int row  = rowbase + r16;                 // rowbase multiple of 16 -> row&7 == r16&7
  int slot = (g + 4 * kk) ^ (r16 & 7);
  return *(const short8*)(lds + (size_t)row * 64 + (size_t)slot * 8);
}

// ---------------------------------------------------------------------------
__global__ void init_zero_k(float* __restrict__ out, float* __restrict__ norm2) {
  int i = blockIdx.x * 256 + threadIdx.x;
  if (i < ROWS) { out[i] = 0.f; norm2[i] = 0.f; }
}

__global__ void convert_x_k(const float4* __restrict__ x, ushort4* __restrict__ xb, int n4) {
  int i = blockIdx.x * 256 + threadIdx.x;
  if (i < n4) {
    float4 v = x[i];
    ushort4 o;
    o.x = f2bf(v.x); o.y = f2bf(v.y); o.z = f2bf(v.z); o.w = f2bf(v.w);
    xb[i] = o;
  }
}

// Wt[n][k] = W[k][n], bf16.  64x64 tiles via LDS.
__global__ void transpose_w_k(const float* __restrict__ W, unsigned short* __restrict__ Wt) {
  __shared__ unsigned short t[64][65];
  int bx = blockIdx.x & 15;   // col tile of W
  int by = blockIdx.x >> 4;   // row tile of W
  int c  = threadIdx.x & 63;
  int r0 = threadIdx.x >> 6;  // 0..3
#pragma unroll
  for (int i = 0; i < 16; ++i) {
    int r = r0 + i * 4;
    t[r][c] = f2bf(W[(size_t)(by * 64 + r) * DIM + (bx * 64 + c)]);
  }
  __syncthreads();
#pragma unroll
  for (int i = 0; i < 16; ++i) {
    int r = r0 + i * 4;  // row of Wt within tile = original col
    Wt[(size_t)(bx * 64 + r) * DIM + (by * 64 + c)] = t[c][r];
  }
}

// ---------------------------------------------------------------------------
// GEMM1: proj = Xb @ W  (B panel = rows of Wt). Writes bf16 proj + atomic sumsq.
// 2-phase double-buffered pipeline: issue tile t+1 loads BEFORE computing tile t;
// the single __syncthreads per iter drains vmcnt AFTER the MFMAs (T3 min recipe).
__global__ __launch_bounds__(256) void gemm1_proj(
    const unsigned short* __restrict__ Xb,
    const unsigned short* __restrict__ Wt,
    unsigned short* __restrict__ projb,
    float* __restrict__ norm2) {
  __shared__ __align__(16) unsigned short lA[2 * TILE];
  __shared__ __align__(16) unsigned short lB[2 * TILE];
  const int tid = threadIdx.x;
  const int lane = tid & 63, wv = tid >> 6;
  const int wr = wv >> 1, wc = wv & 1;
  const int g = lane >> 4, r16 = lane & 15;
  const int mt = blockIdx.x >> 3, nt = blockIdx.x & 7;
  const int arow0 = mt * 128, brow0 = nt * 128;

  f32x4 acc[4][4];
#pragma unroll
  for (int m = 0; m < 4; ++m)
#pragma unroll
    for (int n = 0; n < 4; ++n) acc[m][n] = (f32x4){0.f, 0.f, 0.f, 0.f};

  // prologue: stage tile 0 into buffer 0
  stage_tile(Xb, arow0, 0, lA, tid);
  stage_tile(Wt, brow0, 0, lB, tid);
  __syncthreads();

  for (int kt = 0; kt < DIM / 64; ++kt) {
    const int cur = kt & 1, nxt = cur ^ 1;
    if (kt + 1 < DIM / 64) {
      stage_tile(Xb, arow0, (kt + 1) * 64, lA + nxt * TILE, tid);
      stage_tile(Wt, brow0, (kt + 1) * 64, lB + nxt * TILE, tid);
    }
    const unsigned short* Abuf = lA + cur * TILE;
    const unsigned short* Bbuf = lB + cur * TILE;
#pragma unroll
    for (int kk = 0; kk < 2; ++kk) {
      short8 af[4], bfr[4];
#pragma unroll
      for (int m = 0; m < 4; ++m) af[m] = read_frag(Abuf, wr * 64 + m * 16, r16, g, kk);
#pragma unroll
      for (int n = 0; n < 4; ++n) bfr[n] = read_frag(Bbuf, wc * 64 + n * 16, r16, g, kk);
#pragma unroll
      for (int m = 0; m < 4; ++m)
#pragma unroll
        for (int n = 0; n < 4; ++n)
          acc[m][n] = mfma16(af[m], bfr[n], acc[m][n]);
    }
    __syncthreads();  // drains vmcnt(0)+lgkmcnt(0): tile kt+1 landed, all reads of kt done
  }

  // Epilogue: bf16 store + per-row sum-of-squares (reduce over lane&15 = cols).
#pragma unroll
  for (int m = 0; m < 4; ++m) {
#pragma unroll
    for (int r = 0; r < 4; ++r) {
      int row = arow0 + wr * 64 + m * 16 + 4 * g + r;
      float ss = 0.f;
#pragma unroll
      for (int n = 0; n < 4; ++n) {
        float v = acc[m][n][r];
        projb[(size_t)row * DIM + (brow0 + wc * 64 + n * 16 + r16)] = f2bf(v);
        ss += v * v;
      }
      ss += __shfl_xor(ss, 1);
      ss += __shfl_xor(ss, 2);
      ss += __shfl_xor(ss, 4);
      ss += __shfl_xor(ss, 8);
      if (r16 == 0) atomicAdd(&norm2[row], ss);
    }
  }
}

// ---------------------------------------------------------------------------
// GEMM2 (symmetric, 2-phase pipelined): only tiles st <= tt. Raw-dot MFMA on
// unnormalized projb; epilogue scales by rs_s*rs_t, sigmoid, col-sums + (off-
// diagonal) row-sums by symmetry. Natural dispatch order (R3) — XCD remap
// measured -11%, reverted.
__global__ __launch_bounds__(256) void gemm2_attn(
    const unsigned short* __restrict__ projb,
    const float* __restrict__ norm2,
    float* __restrict__ out) {
  __shared__ __align__(16) unsigned short lA[2 * TILE];
  __shared__ __align__(16) unsigned short lB[2 * TILE];
  const int tid = threadIdx.x;
  const int lane = tid & 63, wv = tid >> 6;
  const int wr = wv >> 1, wc = wv & 1;
  const int g = lane >> 4, r16 = lane & 15;
  const int b = blockIdx.z;

  // Decode triangular pair index p -> (st, tt), st <= tt. Uniform scalar loop.
  int p = blockIdx.x;
  int st = 0, rem = p;
  while (rem >= (NT - st)) { rem -= (NT - st); ++st; }
  const int tt = st + rem;

  const unsigned short* Nb = projb + (size_t)b * SEQ * DIM;
  const float* n2b = norm2 + (size_t)b * SEQ;
  const int arow0 = st * 128, brow0 = tt * 128;
  const bool diag = (st == tt);

  f32x4 acc[4][4];
#pragma unroll
  for (int m = 0; m < 4; ++m)
#pragma unroll
    for (int n = 0; n < 4; ++n) acc[m][n] = (f32x4){0.f, 0.f, 0.f, 0.f};

  // prologue
  stage_tile(Nb, arow0, 0, lA, tid);
  if (!diag) stage_tile(Nb, brow0, 0, lB, tid);
  __syncthreads();

  for (int kt = 0; kt < DIM / 64; ++kt) {
    const int cur = kt & 1, nxt = cur ^ 1;
    if (kt + 1 < DIM / 64) {
      stage_tile(Nb, arow0, (kt + 1) * 64, lA + nxt * TILE, tid);
      if (!diag) stage_tile(Nb, brow0, (kt + 1) * 64, lB + nxt * TILE, tid);
    }
    const unsigned short* Abuf = lA + cur * TILE;
    const unsigned short* Bbuf = diag ? Abuf : (lB + cur * TILE);
#pragma unroll
    for (int kk = 0; kk < 2; ++kk) {
      short8 af[4], bfr[4];
#pragma unroll
      for (int m = 0; m < 4; ++m) af[m] = read_frag(Abuf, wr * 64 + m * 16, r16, g, kk);
#pragma unroll
      for (int n = 0; n < 4; ++n) bfr[n] = read_frag(Bbuf, wc * 64 + n * 16, r16, g, kk);
#pragma unroll
      for (int m = 0; m < 4; ++m)
#pragma unroll
        for (int n = 0; n < 4; ++n)
          acc[m][n] = mfma16(af[m], bfr[n], acc[m][n]);
    }
    __syncthreads();
  }

  // Inverse norms for my rows (16) and cols (4).  rs = 1/max(sqrt(ss), eps).
  float rs_row[4][4], rs_col[4];
#pragma unroll
  for (int m = 0; m < 4; ++m)
#pragma unroll
    for (int r = 0; r < 4; ++r) {
      int row = arow0 + wr * 64 + m * 16 + 4 * g + r;
      rs_row[m][r] = 1.0f / fmaxf(sqrtf(n2b[row]), 1e-12f);
    }
#pragma unroll
  for (int n = 0; n < 4; ++n) {
    int col = brow0 + wc * 64 + n * 16 + r16;
    rs_col[n] = 1.0f / fmaxf(sqrtf(n2b[col]), 1e-12f);
  }

  const float inv = 1.0f / (float)SEQ;
  float rowacc[4][4];
#pragma unroll
  for (int m = 0; m < 4; ++m)
#pragma unroll
    for (int r = 0; r < 4; ++r) rowacc[m][r] = 0.f;

  // Sigmoid each element once; accumulate col partials (per n) + row partials.
#pragma unroll
  for (int n = 0; n < 4; ++n) {
    float colpart = 0.f;
#pragma unroll
    for (int m = 0; m < 4; ++m)
#pragma unroll
      for (int r = 0; r < 4; ++r) {
        float x = acc[m][n][r] * rs_row[m][r] * rs_col[n];
        float s = 1.0f / (1.0f + __expf(-x));
        colpart += s;
        rowacc[m][r] += s;
      }
    // reduce over rows held by other g-groups of this wave
    colpart += __shfl_xor(colpart, 16);
    colpart += __shfl_xor(colpart, 32);
    if (g == 0)
      atomicAdd(&out[(size_t)b * SEQ + brow0 + wc * 64 + n * 16 + r16], colpart * inv);
  }

  if (!diag) {
    // row sums over this wave's 64 cols -> out[s in R] (symmetry).
#pragma unroll
    for (int m = 0; m < 4; ++m)
#pragma unroll
      for (int r = 0; r < 4; ++r) {
        float rp = rowacc[m][r];
        rp += __shfl_xor(rp, 1);
        rp += __shfl_xor(rp, 2);
        rp += __shfl_xor(rp, 4);
        rp += __shfl_xor(rp, 8);
        if (r16 == 0)
          atomicAdd(&out[(size_t)b * SEQ + arow0 + wr * 64 + m * 16 + 4 * g + r], rp * inv);
      }
  }
}

// ---------------------------------------------------------------------------
extern "C" void kernel_launch(void* const* d_in, const int* in_sizes, int n_in,
                              void* d_out, int out_size, void* d_ws, size_t ws_size,
                              hipStream_t stream) {
  const float* x = (const float*)d_in[0];
  const float* W = (const float*)d_in[1];
  float* out = (float*)d_out;

  char* ws = (char*)d_ws;
  unsigned short* Xb    = (unsigned short*)ws;                                   // 64 MiB
  unsigned short* projb = (unsigned short*)(ws + (size_t)ROWS * DIM * 2);        // 64 MiB
  unsigned short* Wt    = (unsigned short*)(ws + (size_t)ROWS * DIM * 4);        // 2 MiB
  float* norm2          = (float*)(ws + (size_t)ROWS * DIM * 4 + (size_t)DIM * DIM * 2);

  hipLaunchKernelGGL(init_zero_k, dim3(ROWS / 256), dim3(256), 0, stream, out, norm2);
  hipLaunchKernelGGL(convert_x_k, dim3((ROWS * DIM / 4) / 256), dim3(256), 0, stream,
                     (const float4*)x, (ushort4*)Xb, ROWS * DIM / 4);
  hipLaunchKernelGGL(transpose_w_k, dim3(256), dim3(256), 0, stream, W, Wt);
  hipLaunchKernelGGL(gemm1_proj, dim3((ROWS / 128) * (DIM / 128)), dim3(256), 0, stream,
                     Xb, Wt, projb, norm2);
  hipLaunchKernelGGL(gemm2_attn, dim3(NPAIR, 1, BATCH), dim3(256), 0, stream,
                     projb, norm2, out);
}

// Round 10
// 505.475 us; speedup vs baseline: 1.0649x; 1.0298x over previous
//
#include <hip/hip_runtime.h>
#include <stdint.h>

#define BATCH 8
#define SEQ   4096
#define DIM   1024
#define ROWS  (BATCH * SEQ)   // 32768
#define NKT   (DIM / 64)      // 16 K-tiles of BK=64
#define SLOT  24576           // elems per ring slot: A 128x64 (8192) + B 256x64 (16384)

typedef __attribute__((ext_vector_type(8))) short short8;
typedef __attribute__((ext_vector_type(4))) float f32x4;

__device__ __forceinline__ unsigned short f2bf(float f) {
  union { float f; unsigned u; } v; v.f = f;
  unsigned r = v.u + 0x7FFFu + ((v.u >> 16) & 1u);  // RNE
  return (unsigned short)(r >> 16);
}

__device__ __forceinline__ void gload_lds16(const unsigned short* g, unsigned short* l) {
  __builtin_amdgcn_global_load_lds(
      (const __attribute__((address_space(1))) void*)g,
      (__attribute__((address_space(3))) void*)l,
      16, 0, 0);
}

__device__ __forceinline__ f32x4 mfma16(short8 a, short8 b, f32x4 c) {
  return __builtin_amdgcn_mfma_f32_16x16x32_bf16(a, b, c, 0, 0, 0);
}

// Stage one K-tile (A: 128 rows, B: 256 rows, 64 k each) into a ring slot.
// 6 gload_lds per thread (512 threads). XOR swizzle (chunk ^ (row&7)) applied
// on the GLOBAL source; LDS dest stays linear (rule #21).
__device__ __forceinline__ void stage_ab(const unsigned short* __restrict__ A, int arow0,
                                         const unsigned short* __restrict__ B, int brow0,
                                         int k0, unsigned short* slot, int tid) {
#pragma unroll
  for (int i = 0; i < 2; ++i) {           // A: 1024 chunks of 16B
    int c = tid + 512 * i;
    int row = c >> 3, h = c & 7, gc = h ^ (row & 7);
    const unsigned short* gp = A + (size_t)(arow0 + row) * DIM + (size_t)(k0 + gc * 8);
    unsigned short* lp = slot + (size_t)((tid & ~63) + 512 * i) * 8;   // wave-uniform base
    gload_lds16(gp, lp);
  }
#pragma unroll
  for (int i = 0; i < 4; ++i) {           // B: 2048 chunks of 16B
    int c = tid + 512 * i;
    int row = c >> 3, h = c & 7, gc = h ^ (row & 7);
    const unsigned short* gp = B + (size_t)(brow0 + row) * DIM + (size_t)(k0 + gc * 8);
    unsigned short* lp = slot + (size_t)(1024 + (tid & ~63) + 512 * i) * 8;
    gload_lds16(gp, lp);
  }
}

// Read one MFMA fragment (row-major panel in slot region), same XOR swizzle.
__device__ __forceinline__ short8 read_frag(const unsigned short* region, int rowbase,
                                            int r16, int g, int kk) {
  int row  = rowbase + r16;               // rowbase multiple of 16 -> row&7 == r16&7
  int slot = (g + 4 * kk) ^ (r16 & 7);
  return *(const short8*)(region + (size_t)row * 64 + (size_t)slot * 8);
}

// Counted-vmcnt ring K-loop shared by both GEMMs. acc[4][4] per wave (64x64).
// wr in {0,1} (x64 rows), wc in {0..3} (x64 cols).
#define RING_K_LOOP(ASRC, AROW0, BSRC, BROW0)                                   \
  stage_ab(ASRC, AROW0, BSRC, BROW0, 0,  lds + 0 * SLOT, tid);                  \
  stage_ab(ASRC, AROW0, BSRC, BROW0, 64, lds + 1 * SLOT, tid);                  \
  for (int t = 0; t < NKT; ++t) {                                               \
    if (t == NKT - 1) { asm volatile("s_waitcnt vmcnt(0)" ::: "memory"); }      \
    else              { asm volatile("s_waitcnt vmcnt(6)" ::: "memory"); }      \
    __builtin_amdgcn_s_barrier();                                               \
    __builtin_amdgcn_sched_barrier(0);                                          \
    if (t + 2 < NKT)                                                            \
      stage_ab(ASRC, AROW0, BSRC, BROW0, (t + 2) * 64,                          \
               lds + ((t + 2) % 3) * SLOT, tid);                                \
    const unsigned short* Ar = lds + (t % 3) * SLOT;                            \
    const unsigned short* Br = Ar + 8192;                                       \
    _Pragma("unroll")                                                           \
    for (int kk = 0; kk < 2; ++kk) {                                            \
      short8 af[4], bfr[4];                                                     \
      _Pragma("unroll")                                                         \
      for (int m = 0; m < 4; ++m) af[m]  = read_frag(Ar, wr * 64 + m * 16, r16, g, kk); \
      _Pragma("unroll")                                                         \
      for (int n = 0; n < 4; ++n) bfr[n] = read_frag(Br, wc * 64 + n * 16, r16, g, kk); \
      _Pragma("unroll")                                                         \
      for (int m = 0; m < 4; ++m)                                               \
        _Pragma("unroll")                                                       \
        for (int n = 0; n < 4; ++n)                                             \
          acc[m][n] = mfma16(af[m], bfr[n], acc[m][n]);                         \
    }                                                                           \
  }

// ---------------------------------------------------------------------------
__global__ void init_zero_k(float* __restrict__ out, float* __restrict__ norm2) {
  int i = blockIdx.x * 256 + threadIdx.x;
  if (i < ROWS) { out[i] = 0.f; norm2[i] = 0.f; }
}

__global__ void convert_x_k(const float4* __restrict__ x, ushort4* __restrict__ xb, int n4) {
  int i = blockIdx.x * 256 + threadIdx.x;
  if (i < n4) {
    float4 v = x[i];
    ushort4 o;
    o.x = f2bf(v.x); o.y = f2bf(v.y); o.z = f2bf(v.z); o.w = f2bf(v.w);
    xb[i] = o;
  }
}

// Wt[n][k] = W[k][n], bf16.  64x64 tiles via LDS.
__global__ void transpose_w_k(const float* __restrict__ W, unsigned short* __restrict__ Wt) {
  __shared__ unsigned short t[64][65];
  int bx = blockIdx.x & 15;
  int by = blockIdx.x >> 4;
  int c  = threadIdx.x & 63;
  int r0 = threadIdx.x >> 6;
#pragma unroll
  for (int i = 0; i < 16; ++i) {
    int r = r0 + i * 4;
    t[r][c] = f2bf(W[(size_t)(by * 64 + r) * DIM + (bx * 64 + c)]);
  }
  __syncthreads();
#pragma unroll
  for (int i = 0; i < 16; ++i) {
    int r = r0 + i * 4;
    Wt[(size_t)(bx * 64 + r) * DIM + (by * 64 + c)] = t[c][r];
  }
}

// ---------------------------------------------------------------------------
// GEMM1: proj = Xb @ W. 128x256 tile, 8 waves, 3-slot counted-vmcnt ring.
__global__ __launch_bounds__(512, 2) void gemm1_proj(
    const unsigned short* __restrict__ Xb,
    const unsigned short* __restrict__ Wt,
    unsigned short* __restrict__ projb,
    float* __restrict__ norm2) {
  __shared__ __align__(16) unsigned short lds[3 * SLOT];   // 144 KiB
  const int tid = threadIdx.x;
  const int lane = tid & 63, wv = tid >> 6;
  const int wr = wv >> 2, wc = wv & 3;
  const int g = lane >> 4, r16 = lane & 15;
  const int mt = blockIdx.x >> 2, u = blockIdx.x & 3;
  const int arow0 = mt * 128, brow0 = u * 256;

  f32x4 acc[4][4];
#pragma unroll
  for (int m = 0; m < 4; ++m)
#pragma unroll
    for (int n = 0; n < 4; ++n) acc[m][n] = (f32x4){0.f, 0.f, 0.f, 0.f};

  RING_K_LOOP(Xb, arow0, Wt, brow0)

  // Epilogue: bf16 store + per-row sum-of-squares.
#pragma unroll
  for (int m = 0; m < 4; ++m) {
#pragma unroll
    for (int r = 0; r < 4; ++r) {
      int row = arow0 + wr * 64 + m * 16 + 4 * g + r;
      float ss = 0.f;
#pragma unroll
      for (int n = 0; n < 4; ++n) {
        float v = acc[m][n][r];
        projb[(size_t)row * DIM + (brow0 + wc * 64 + n * 16 + r16)] = f2bf(v);
        ss += v * v;
      }
      ss += __shfl_xor(ss, 1);
      ss += __shfl_xor(ss, 2);
      ss += __shfl_xor(ss, 4);
      ss += __shfl_xor(ss, 8);
      if (r16 == 0) atomicAdd(&norm2[row], ss);
    }
  }
}

// ---------------------------------------------------------------------------
// GEMM2 (symmetric): block = (st: 128 A-rows) x (u: 256 B-cols = tt in {2u,2u+1}),
// kept iff st <= 2u+1. Per-wave col range lies in ONE base tile tt_wave:
//   tt_wave < st  -> masked (mirror computed elsewhere)
//   tt_wave == st -> diagonal: col-sums only (full square counted once)
//   tt_wave > st  -> col-sums + row-sums (symmetry)
__global__ __launch_bounds__(512, 2) void gemm2_attn(
    const unsigned short* __restrict__ projb,
    const float* __restrict__ norm2,
    float* __restrict__ out) {
  __shared__ __align__(16) unsigned short lds[3 * SLOT];   // 144 KiB
  const int tid = threadIdx.x;
  const int lane = tid & 63, wv = tid >> 6;
  const int wr = wv >> 2, wc = wv & 3;
  const int g = lane >> 4, r16 = lane & 15;
  const int b = blockIdx.z;

  // Decode q -> (u, st): per u there are 2u+2 st values (0..2u+1).
  int q = blockIdx.x;
  int u = 0;
  while (q >= 2 * u + 2) { q -= 2 * u + 2; ++u; }
  const int st = q;

  const unsigned short* Nb = projb + (size_t)b * SEQ * DIM;
  const float* n2b = norm2 + (size_t)b * SEQ;
  const int arow0 = st * 128, brow0 = u * 256;

  f32x4 acc[4][4];
#pragma unroll
  for (int m = 0; m < 4; ++m)
#pragma unroll
    for (int n = 0; n < 4; ++n) acc[m][n] = (f32x4){0.f, 0.f, 0.f, 0.f};

  RING_K_LOOP(Nb, arow0, Nb, brow0)

  const int tt_wave = 2 * u + (wc >> 1);
  const bool do_col = (tt_wave >= st);
  const bool do_row = (tt_wave > st);

  // Inverse norms. rs = 1/max(sqrt(ss), eps)  (matches torch F.normalize).
  float rs_row[4][4], rs_col[4];
#pragma unroll
  for (int m = 0; m < 4; ++m)
#pragma unroll
    for (int r = 0; r < 4; ++r) {
      int row = arow0 + wr * 64 + m * 16 + 4 * g + r;
      rs_row[m][r] = 1.0f / fmaxf(sqrtf(n2b[row]), 1e-12f);
    }
#pragma unroll
  for (int n = 0; n < 4; ++n) {
    int col = brow0 + wc * 64 + n * 16 + r16;
    rs_col[n] = 1.0f / fmaxf(sqrtf(n2b[col]), 1e-12f);
  }

  const float inv = 1.0f / (float)SEQ;
  float rowacc[4][4];
#pragma unroll
  for (int m = 0; m < 4; ++m)
#pragma unroll
    for (int r = 0; r < 4; ++r) rowacc[m][r] = 0.f;

  if (do_col) {
#pragma unroll
    for (int n = 0; n < 4; ++n) {
      float colpart = 0.f;
#pragma unroll
      for (int m = 0; m < 4; ++m)
#pragma unroll
        for (int r = 0; r < 4; ++r) {
          float xv = acc[m][n][r] * rs_row[m][r] * rs_col[n];
          float s = 1.0f / (1.0f + __expf(-xv));
          colpart += s;
          rowacc[m][r] += s;
        }
      colpart += __shfl_xor(colpart, 16);
      colpart += __shfl_xor(colpart, 32);
      if (g == 0)
        atomicAdd(&out[(size_t)b * SEQ + brow0 + wc * 64 + n * 16 + r16], colpart * inv);
    }
  }

  if (do_row) {
#pragma unroll
    for (int m = 0; m < 4; ++m)
#pragma unroll
      for (int r = 0; r < 4; ++r) {
        float rp = rowacc[m][r];
        rp += __shfl_xor(rp, 1);
        rp += __shfl_xor(rp, 2);
        rp += __shfl_xor(rp, 4);
        rp += __shfl_xor(rp, 8);
        if (r16 == 0)
          atomicAdd(&out[(size_t)b * SEQ + arow0 + wr * 64 + m * 16 + 4 * g + r], rp * inv);
      }
  }
}

// ---------------------------------------------------------------------------
extern "C" void kernel_launch(void* const* d_in, const int* in_sizes, int n_in,
                              void* d_out, int out_size, void* d_ws, size_t ws_size,
                              hipStream_t stream) {
  const float* x = (const float*)d_in[0];
  const float* W = (const float*)d_in[1];
  float* out = (float*)d_out;

  char* ws = (char*)d_ws;
  unsigned short* Xb    = (unsigned short*)ws;                                   // 64 MiB
  unsigned short* projb = (unsigned short*)(ws + (size_t)ROWS * DIM * 2);        // 64 MiB
  unsigned short* Wt    = (unsigned short*)(ws + (size_t)ROWS * DIM * 4);        // 2 MiB
  float* norm2          = (float*)(ws + (size_t)ROWS * DIM * 4 + (size_t)DIM * DIM * 2);

  hipLaunchKernelGGL(init_zero_k, dim3(ROWS / 256), dim3(256), 0, stream, out, norm2);
  hipLaunchKernelGGL(convert_x_k, dim3((ROWS * DIM / 4) / 256), dim3(256), 0, stream,
                     (const float4*)x, (ushort4*)Xb, ROWS * DIM / 4);
  hipLaunchKernelGGL(transpose_w_k, dim3(256), dim3(256), 0, stream, W, Wt);
  // GEMM1: 256 mt-tiles x 4 u-tiles
  hipLaunchKernelGGL(gemm1_proj, dim3((ROWS / 128) * (DIM / 256)), dim3(512), 0, stream,
                     Xb, Wt, projb, norm2);
  // GEMM2: per batch, sum_{u=0..15} (2u+2) = 272 blocks
  hipLaunchKernelGGL(gemm2_attn, dim3(272, 1, BATCH), dim3(512), 0, stream,
                     projb, norm2, out);
}

// Round 11
// 482.655 us; speedup vs baseline: 1.1153x; 1.0473x over previous
//
#include <hip/hip_runtime.h>
#include <stdint.h>

#define BATCH 8
#define SEQ   4096
#define DIM   1024
#define ROWS  (BATCH * SEQ)   // 32768
#define NKT   (DIM / 64)      // 16 K-tiles of BK=64
#define HALF  16384           // elems per 256x64 panel
#define SLOT  32768           // elems per ring slot: A panel + B panel

typedef __attribute__((ext_vector_type(8))) short short8;
typedef __attribute__((ext_vector_type(4))) float f32x4;

__device__ __forceinline__ unsigned short f2bf(float f) {
  union { float f; unsigned u; } v; v.f = f;
  unsigned r = v.u + 0x7FFFu + ((v.u >> 16) & 1u);  // RNE
  return (unsigned short)(r >> 16);
}

__device__ __forceinline__ void gload_lds16(const unsigned short* g, unsigned short* l) {
  __builtin_amdgcn_global_load_lds(
      (const __attribute__((address_space(1))) void*)g,
      (__attribute__((address_space(3))) void*)l,
      16, 0, 0);
}

__device__ __forceinline__ f32x4 mfma16(short8 a, short8 b, f32x4 c) {
  return __builtin_amdgcn_mfma_f32_16x16x32_bf16(a, b, c, 0, 0, 0);
}

// Stage one 256x64 bf16 panel into an LDS region (linear dest, pre-swizzled
// global source: chunk ^ (row&7), rule #21). 4 gload_lds per thread (512 thr).
__device__ __forceinline__ void stage_panel(const unsigned short* __restrict__ src,
                                            int row0, int k0,
                                            unsigned short* region, int tid) {
#pragma unroll
  for (int i = 0; i < 4; ++i) {
    int c = tid + 512 * i;                // 2048 chunks of 16B
    int row = c >> 3, h = c & 7, gc = h ^ (row & 7);
    const unsigned short* gp = src + (size_t)(row0 + row) * DIM + (size_t)(k0 + gc * 8);
    unsigned short* lp = region + (size_t)((tid & ~63) + 512 * i) * 8;  // wave-uniform base
    gload_lds16(gp, lp);
  }
}

// Read one MFMA fragment (row-major panel, row stride 64), same XOR swizzle.
__device__ __forceinline__ short8 read_frag(const unsigned short* region, int rowbase,
                                            int r16, int g, int kk) {
  int row  = rowbase + r16;               // rowbase multiple of 16 -> row&7 == r16&7
  int slot = (g + 4 * kk) ^ (r16 & 7);
  return *(const short8*)(region + (size_t)row * 64 + (size_t)slot * 8);
}

// Reordered 2-slot pipeline: wait+barrier at TOP (slot t ready), THEN issue
// stage(t+1) (full compute(t) of latency cover), then compute(t).
// DIAG (block-uniform): B panel == A panel, stage A only.
#define RING2_K_LOOP(ASRC, AROW0, BSRC, BROW0, DIAG)                            \
  stage_panel(ASRC, AROW0, 0, lds, tid);                                        \
  if (!(DIAG)) stage_panel(BSRC, BROW0, 0, lds + HALF, tid);                    \
  for (int t = 0; t < NKT; ++t) {                                               \
    asm volatile("s_waitcnt vmcnt(0)" ::: "memory");                            \
    __builtin_amdgcn_s_barrier();                                               \
    __builtin_amdgcn_sched_barrier(0);                                          \
    const int cslot = t & 1;                                                    \
    if (t + 1 < NKT) {                                                          \
      stage_panel(ASRC, AROW0, (t + 1) * 64, lds + (1 - cslot) * SLOT, tid);    \
      if (!(DIAG))                                                              \
        stage_panel(BSRC, BROW0, (t + 1) * 64, lds + (1 - cslot) * SLOT + HALF, tid); \
    }                                                                           \
    const unsigned short* Ar = lds + cslot * SLOT;                              \
    const unsigned short* Br = (DIAG) ? Ar : (Ar + HALF);                       \
    _Pragma("unroll")                                                           \
    for (int kk = 0; kk < 2; ++kk) {                                            \
      short8 af[8], bfr[4];                                                     \
      _Pragma("unroll")                                                         \
      for (int m = 0; m < 8; ++m) af[m]  = read_frag(Ar, wr * 128 + m * 16, r16, g, kk); \
      _Pragma("unroll")                                                         \
      for (int n = 0; n < 4; ++n) bfr[n] = read_frag(Br, wc * 64 + n * 16, r16, g, kk);  \
      _Pragma("unroll")                                                         \
      for (int m = 0; m < 8; ++m)                                               \
        _Pragma("unroll")                                                       \
        for (int n = 0; n < 4; ++n)                                             \
          acc[m][n] = mfma16(af[m], bfr[n], acc[m][n]);                         \
    }                                                                           \
  }

// ---------------------------------------------------------------------------
__global__ void init_zero_k(float* __restrict__ out, float* __restrict__ norm2) {
  int i = blockIdx.x * 256 + threadIdx.x;
  if (i < ROWS) { out[i] = 0.f; norm2[i] = 0.f; }
}

__global__ void convert_x_k(const float4* __restrict__ x, ushort4* __restrict__ xb, int n4) {
  int i = blockIdx.x * 256 + threadIdx.x;
  if (i < n4) {
    float4 v = x[i];
    ushort4 o;
    o.x = f2bf(v.x); o.y = f2bf(v.y); o.z = f2bf(v.z); o.w = f2bf(v.w);
    xb[i] = o;
  }
}

// Wt[n][k] = W[k][n], bf16.  64x64 tiles via LDS.
__global__ void transpose_w_k(const float* __restrict__ W, unsigned short* __restrict__ Wt) {
  __shared__ unsigned short t[64][65];
  int bx = blockIdx.x & 15;
  int by = blockIdx.x >> 4;
  int c  = threadIdx.x & 63;
  int r0 = threadIdx.x >> 6;
#pragma unroll
  for (int i = 0; i < 16; ++i) {
    int r = r0 + i * 4;
    t[r][c] = f2bf(W[(size_t)(by * 64 + r) * DIM + (bx * 64 + c)]);
  }
  __syncthreads();
#pragma unroll
  for (int i = 0; i < 16; ++i) {
    int r = r0 + i * 4;
    Wt[(size_t)(bx * 64 + r) * DIM + (by * 64 + c)] = t[c][r];
  }
}

// ---------------------------------------------------------------------------
// GEMM1: proj = Xb @ W. 256x256 tile, 8 waves (2x4), 2-slot reordered ring.
__global__ __launch_bounds__(512, 2) void gemm1_proj(
    const unsigned short* __restrict__ Xb,
    const unsigned short* __restrict__ Wt,
    unsigned short* __restrict__ projb,
    float* __restrict__ norm2) {
  __shared__ __align__(16) unsigned short lds[2 * SLOT];   // 128 KiB
  const int tid = threadIdx.x;
  const int lane = tid & 63, wv = tid >> 6;
  const int wr = wv >> 2, wc = wv & 3;                     // 2 x 4 waves
  const int g = lane >> 4, r16 = lane & 15;
  const int mt = blockIdx.x >> 2, u = blockIdx.x & 3;
  const int arow0 = mt * 256, brow0 = u * 256;

  f32x4 acc[8][4];
#pragma unroll
  for (int m = 0; m < 8; ++m)
#pragma unroll
    for (int n = 0; n < 4; ++n) acc[m][n] = (f32x4){0.f, 0.f, 0.f, 0.f};

  RING2_K_LOOP(Xb, arow0, Wt, brow0, false)

  // Epilogue: bf16 store + per-row sum-of-squares.
#pragma unroll
  for (int m = 0; m < 8; ++m) {
#pragma unroll
    for (int r = 0; r < 4; ++r) {
      int row = arow0 + wr * 128 + m * 16 + 4 * g + r;
      float ss = 0.f;
#pragma unroll
      for (int n = 0; n < 4; ++n) {
        float v = acc[m][n][r];
        projb[(size_t)row * DIM + (brow0 + wc * 64 + n * 16 + r16)] = f2bf(v);
        ss += v * v;
      }
      ss += __shfl_xor(ss, 1);
      ss += __shfl_xor(ss, 2);
      ss += __shfl_xor(ss, 4);
      ss += __shfl_xor(ss, 8);
      if (r16 == 0) atomicAdd(&norm2[row], ss);
    }
  }
}

// ---------------------------------------------------------------------------
// GEMM2 (symmetric, 256x256 tiles): pairs (st <= u), 136 per batch.
// diag (st==u): full square computed once -> col-sums only; B panel = A panel.
// off-diag: col-sums (-> out[t in u]) + row-sums (-> out[s in st], symmetry).
__global__ __launch_bounds__(512, 2) void gemm2_attn(
    const unsigned short* __restrict__ projb,
    const float* __restrict__ norm2,
    float* __restrict__ out) {
  __shared__ __align__(16) unsigned short lds[2 * SLOT];   // 128 KiB
  const int tid = threadIdx.x;
  const int lane = tid & 63, wv = tid >> 6;
  const int wr = wv >> 2, wc = wv & 3;
  const int g = lane >> 4, r16 = lane & 15;
  const int b = blockIdx.z;

  // Decode q -> (u, st), u-major: for u, st = 0..u  (consecutive blocks share B panel).
  int q = blockIdx.x;
  int u = 0;
  while (q >= u + 1) { q -= u + 1; ++u; }
  const int st = q;
  const bool diag = (st == u);

  const unsigned short* Nb = projb + (size_t)b * SEQ * DIM;
  const float* n2b = norm2 + (size_t)b * SEQ;
  const int arow0 = st * 256, brow0 = u * 256;

  f32x4 acc[8][4];
#pragma unroll
  for (int m = 0; m < 8; ++m)
#pragma unroll
    for (int n = 0; n < 4; ++n) acc[m][n] = (f32x4){0.f, 0.f, 0.f, 0.f};

  RING2_K_LOOP(Nb, arow0, Nb, brow0, diag)

  // Inverse norms. rs = 1/max(sqrt(ss), eps)  (matches torch F.normalize).
  float rs_row[8][4], rs_col[4];
#pragma unroll
  for (int m = 0; m < 8; ++m)
#pragma unroll
    for (int r = 0; r < 4; ++r) {
      int row = arow0 + wr * 128 + m * 16 + 4 * g + r;
      rs_row[m][r] = 1.0f / fmaxf(sqrtf(n2b[row]), 1e-12f);
    }
#pragma unroll
  for (int n = 0; n < 4; ++n) {
    int col = brow0 + wc * 64 + n * 16 + r16;
    rs_col[n] = 1.0f / fmaxf(sqrtf(n2b[col]), 1e-12f);
  }

  const float inv = 1.0f / (float)SEQ;
  float rowacc[8][4];
#pragma unroll
  for (int m = 0; m < 8; ++m)
#pragma unroll
    for (int r = 0; r < 4; ++r) rowacc[m][r] = 0.f;

  // Sigmoid each element once; col partials always, row partials for off-diag.
#pragma unroll
  for (int n = 0; n < 4; ++n) {
    float colpart = 0.f;
#pragma unroll
    for (int m = 0; m < 8; ++m)
#pragma unroll
      for (int r = 0; r < 4; ++r) {
        float xv = acc[m][n][r] * rs_row[m][r] * rs_col[n];
        float s = 1.0f / (1.0f + __expf(-xv));
        colpart += s;
        rowacc[m][r] += s;
      }
    colpart += __shfl_xor(colpart, 16);
    colpart += __shfl_xor(colpart, 32);
    if (g == 0)
      atomicAdd(&out[(size_t)b * SEQ + brow0 + wc * 64 + n * 16 + r16], colpart * inv);
  }

  if (!diag) {
#pragma unroll
    for (int m = 0; m < 8; ++m)
#pragma unroll
      for (int r = 0; r < 4; ++r) {
        float rp = rowacc[m][r];
        rp += __shfl_xor(rp, 1);
        rp += __shfl_xor(rp, 2);
        rp += __shfl_xor(rp, 4);
        rp += __shfl_xor(rp, 8);
        if (r16 == 0)
          atomicAdd(&out[(size_t)b * SEQ + arow0 + wr * 128 + m * 16 + 4 * g + r], rp * inv);
      }
  }
}

// ---------------------------------------------------------------------------
extern "C" void kernel_launch(void* const* d_in, const int* in_sizes, int n_in,
                              void* d_out, int out_size, void* d_ws, size_t ws_size,
                              hipStream_t stream) {
  const float* x = (const float*)d_in[0];
  const float* W = (const float*)d_in[1];
  float* out = (float*)d_out;

  char* ws = (char*)d_ws;
  unsigned short* Xb    = (unsigned short*)ws;                                   // 64 MiB
  unsigned short* projb = (unsigned short*)(ws + (size_t)ROWS * DIM * 2);        // 64 MiB
  unsigned short* Wt    = (unsigned short*)(ws + (size_t)ROWS * DIM * 4);        // 2 MiB
  float* norm2          = (float*)(ws + (size_t)ROWS * DIM * 4 + (size_t)DIM * DIM * 2);

  hipLaunchKernelGGL(init_zero_k, dim3(ROWS / 256), dim3(256), 0, stream, out, norm2);
  hipLaunchKernelGGL(convert_x_k, dim3((ROWS * DIM / 4) / 256), dim3(256), 0, stream,
                     (const float4*)x, (ushort4*)Xb, ROWS * DIM / 4);
  hipLaunchKernelGGL(transpose_w_k, dim3(256), dim3(256), 0, stream, W, Wt);
  // GEMM1: 128 mt-tiles x 4 u-tiles
  hipLaunchKernelGGL(gemm1_proj, dim3((ROWS / 256) * (DIM / 256)), dim3(512), 0, stream,
                     Xb, Wt, projb, norm2);
  // GEMM2: per batch, 16*17/2 = 136 blocks
  hipLaunchKernelGGL(gemm2_attn, dim3(136, 1, BATCH), dim3(512), 0, stream,
                     projb, norm2, out);
}